// Round 5
// baseline (110.381 us; speedup 1.0000x reference)
//
#include <hip/hip_runtime.h>

#define NTOK 32
#define PADT 1
#define MLEN 512
#define NLEN 1024
#define EPS_F 1e-7f

#define RCH 128
#define NC  4
#define NWAVE 4
#define NPHASE (NC + NWAVE - 1)   // 7

// LDS float offsets
#define OFF_P0    0                        // P0[1024]
#define OFF_BND   1024                     // bnd[3 ifaces][2 parity][256]
#define OFF_TOKB  (OFF_BND + 6*256)        // 2560: packed token BYTES (896 B = 224 dwords)
#define OFF_WT    (OFF_TOKB + 224)         // 2784: scan temps (16)
#define OFF_NL    (OFF_WT + 16)            // 2800: nl[32][1024]
#define OFF_SCR   (OFF_NL + NTOK*NLEN)     // 35568: wave-3 dead export scratch (256)
#define LDS_FLOATS (OFF_SCR + 256)

__device__ __forceinline__ float min3f(float a, float b, float c) {
  return fminf(fminf(a, b), c);
}
__device__ __forceinline__ float dpp_shr1(float old_v, float src) {
  return __int_as_float(__builtin_amdgcn_update_dpp(
      __float_as_int(old_v), __float_as_int(src), 0x138, 0xF, 0xF, false));
}
__device__ __forceinline__ unsigned fbyte(unsigned lo, unsigned hi, int a0) {
  return (unsigned)(((((unsigned long long)hi) << 32) | lo) >> (8 * a0));
}

template <bool MASKED>
__device__ __forceinline__ void do_iter(
    int s0, int lane, bool wzero,
    const int* __restrict__ tokd, int& dn,
    const float* __restrict__ nlJ,
    const float* __restrict__ bndR, float* __restrict__ bndW,
    int a0, int& W0, int& W1, int& W2,
    unsigned XKc0, unsigned XKc1, unsigned& XKn0, unsigned& XKn1,
    float4 (&SBc)[8], float (&INJc)[8],
    float4 (&SBn)[8], float (&INJn)[8],
    float4 ri, float cbase,
    float& vp0, float& vp1, float& vp2, float& vp3,
    float& dgL, float& m3p,
    float& wq0, float& wq1, float& wq2, float& wq3,
    float& ans, int qh)
{
  // ---- issue next-iter DS loads first (consumed next call) ----
  int Wa = tokd[dn];
  int Wb = tokd[dn + 1];
#pragma unroll
  for (int k = 0; k < 4; ++k)
    SBn[k] = *(const float4*)(nlJ + ((size_t)((XKc0 >> (8 * k)) & 0xFFu) << 10));
#pragma unroll
  for (int k = 0; k < 4; ++k)
    SBn[4 + k] = *(const float4*)(nlJ + ((size_t)((XKc1 >> (8 * k)) & 0xFFu) << 10));
  if (wzero) {
    float f = cbase + (float)(s0 + 8);
#pragma unroll
    for (int k = 0; k < 8; ++k) INJn[k] = f + (float)k;
  } else {
    float4 ja = *(const float4*)(bndR + s0 + 8);
    float4 jb = *(const float4*)(bndR + s0 + 12);
    INJn[0] = ja.x; INJn[1] = ja.y; INJn[2] = ja.z; INJn[3] = ja.w;
    INJn[4] = jb.x; INJn[5] = jb.y; INJn[6] = jb.z; INJn[7] = jb.w;
  }
  // next-iter gather keys: tokens for slots s0+16..s0+23 (window loaded last iter)
  XKn0 = fbyte((unsigned)W0, (unsigned)W1, a0);
  XKn1 = fbyte((unsigned)W1, (unsigned)W2, a0);

  // ---- compute 8 slots from prev-iter registers only ----
  const int q0 = s0 - lane;
#pragma unroll
  for (int k = 0; k < 8; ++k) {
    const int q = q0 + k;
    float Lnow = dpp_shr1(INJc[k], m3p);
    float m0 = min3f(dgL + SBc[k].x, vp0 + 1.0f, Lnow + ri.x);
    float m1 = min3f(vp0 + SBc[k].y, vp1 + 1.0f, m0 + ri.y);
    float m2 = min3f(vp1 + SBc[k].z, vp2 + 1.0f, m1 + ri.z);
    float m3 = min3f(vp2 + SBc[k].w, vp3 + 1.0f, m2 + ri.w);
    if (MASKED) {
      bool act = ((unsigned)q) < 128u;
      bool lt  = (q < 128);
      dgL = lt ? Lnow : dgL;
      vp0 = act ? m0 : vp0;  vp1 = act ? m1 : vp1;
      vp2 = act ? m2 : vp2;  vp3 = act ? m3 : vp3;
      m3p = act ? m3 : m3p;
      if (act && q == qh) ans = m3;
    } else {
      dgL = Lnow; vp0 = m0; vp1 = m1; vp2 = m2; vp3 = m3; m3p = m3;
      if (q == qh) ans = m3;
    }
    switch ((k + 1) & 3) {
      case 0: wq0 = m3; break; case 1: wq1 = m3; break;
      case 2: wq2 = m3; break; case 3: wq3 = m3; break;
    }
    if (k == 2 || k == 6) {
      int q63 = s0 + k - 63;
      if (lane == 63 && q63 >= 3 && q63 < 128)
        *(float4*)(bndW + (q63 - 3)) = make_float4(wq0, wq1, wq2, wq3);
    }
  }
  W0 = W2; W1 = Wa; W2 = Wb; dn += 2;
}

__global__ __launch_bounds__(256, 1) void align_loss_kernel(
    const int* __restrict__ y_true, const float* __restrict__ y_pred,
    float* __restrict__ partial)
{
  extern __shared__ float smem[];
  float* P0    = smem + OFF_P0;
  float* bnd   = smem + OFF_BND;
  unsigned char* tokb = (unsigned char*)(smem + OFF_TOKB);
  const int* tokd = (const int*)(smem + OFF_TOKB);
  float* wtmp  = smem + OFF_WT;
  int*   wti   = (int*)wtmp;
  float* nl    = smem + OFF_NL;
  float* scr   = smem + OFF_SCR;

  const int b = blockIdx.x;
  const int t = threadIdx.x;
  const int lane = t & 63;
  const int wv = t >> 6;
  const bool wzero = (wv == 0);

  if (t < 224) ((int*)tokb)[t] = 0;
  __syncthreads();

  // ---- Phase A: left-shift compaction -> packed bytes at tokb[64+i] ----
  int total = 0;
  for (int h = 0; h < 2; ++h) {
    int yt = y_true[b * MLEN + h * 256 + t];
    bool f = (yt != PADT);
    unsigned long long m = __ballot(f);
    int wp = __popcll(m & ((1ull << lane) - 1ull));
    if (lane == 0) wti[8 + wv] = __popcll(m);
    __syncthreads();
    int offs = total, ht = 0;
#pragma unroll
    for (int w2 = 0; w2 < NWAVE; ++w2) { int cnt = wti[8 + w2]; if (w2 < wv) offs += cnt; ht += cnt; }
    if (f) tokb[64 + offs + wp] = (unsigned char)yt;
    total += ht;
    __syncthreads();
  }
  const int L = total;

  // ---- Phase B: nl[tk][r] = -log(clip(y_pred[b,r,tk]/sum)) ----
  for (int r = t; r < NLEN; r += 256) {
    const float4* rp = (const float4*)(y_pred + ((size_t)b * NLEN + r) * NTOK);
    float4 q[8]; float s = 0.f;
#pragma unroll
    for (int u = 0; u < 8; ++u) { q[u] = rp[u]; s += q[u].x + q[u].y + q[u].z + q[u].w; }
    float inv = 1.0f / s;
#pragma unroll
    for (int u = 0; u < 8; ++u) {
      float pv[4] = {q[u].x, q[u].y, q[u].z, q[u].w};
#pragma unroll
      for (int c2 = 0; c2 < 4; ++c2) {
        float p = pv[c2] * inv;
        p = fminf(fmaxf(p, EPS_F), 1.0f - EPS_F);
        nl[(u * 4 + c2) * NLEN + r] = -__logf(p);
      }
    }
  }
  __syncthreads();

  // ---- Row-0 prefix: P0[m] = V[0][m+1] ----
  {
    float4 iv = *(const float4*)(nl + PADT * NLEN + 4 * t);
    float p1 = iv.x, p2 = iv.x + iv.y, p3 = p2 + iv.z, s4 = p3 + iv.w;
    float x = s4;
#pragma unroll
    for (int d = 1; d < 64; d <<= 1) {
      float y = __shfl_up(x, d);
      if (lane >= d) x += y;
    }
    if (lane == 63) wtmp[wv] = x;
    __syncthreads();
    float pre = x - s4;
#pragma unroll
    for (int w2 = 0; w2 < NWAVE; ++w2) if (w2 < wv) pre += wtmp[w2];
    *(float4*)(P0 + 4 * t) = make_float4(pre + p1, pre + p2, pre + p3, pre + s4);
  }
  __syncthreads();

  // ---- per-lane persistent DP state ----
  const int J = 256 * wv + 4 * lane;
  const float* nlJ = nl + J;
  float4 ri = *(const float4*)(nl + PADT * NLEN + J);
  float4 vpi = *(const float4*)(P0 + J);
  float vp0 = vpi.x, vp1 = vpi.y, vp2 = vpi.z, vp3 = vpi.w;
  float m3p = vp3;
  float dgL = 0.0f;
  if (J > 0) dgL = P0[J - 1];
  float wq0 = 0, wq1 = 0, wq2 = 0, wq3 = 0, ans = 0.0f;

  // ---- transposed systolic phases ----
  for (int p = 0; p < NPHASE; ++p) {
    __syncthreads();
    const int c = p - wv;
    if (c < 0 || c >= NC) continue;
    const float* bndR = wzero ? P0 : (bnd + ((wv - 1) * 2 + (c & 1)) * 256);
    float* bndW = (wv < 3) ? (bnd + (wv * 2 + (c & 1)) * 256) : scr;
    const int qh = L - 1 - c * RCH;
    const float cbase = (float)(c * RCH + 1);

    // ---- priming ----
    const int B0buf = 64 + c * RCH - lane;
    const int a0 = B0buf & 3;
    int dn = B0buf >> 2;
    int D0 = tokd[dn], D1 = tokd[dn+1], D2 = tokd[dn+2], D3 = tokd[dn+3],
        D4 = tokd[dn+4], D5 = tokd[dn+5], D6 = tokd[dn+6];
    unsigned XA0 = fbyte((unsigned)D0, (unsigned)D1, a0);
    unsigned XA1 = fbyte((unsigned)D1, (unsigned)D2, a0);
    unsigned XKc0 = fbyte((unsigned)D2, (unsigned)D3, a0);
    unsigned XKc1 = fbyte((unsigned)D3, (unsigned)D4, a0);
    float4 SBc[8], SBn[8]; float INJc[8], INJn[8];
    unsigned XKn0, XKn1;
#pragma unroll
    for (int k = 0; k < 4; ++k)
      SBc[k] = *(const float4*)(nlJ + ((size_t)((XA0 >> (8 * k)) & 0xFFu) << 10));
#pragma unroll
    for (int k = 0; k < 4; ++k)
      SBc[4 + k] = *(const float4*)(nlJ + ((size_t)((XA1 >> (8 * k)) & 0xFFu) << 10));
    if (wzero) {
#pragma unroll
      for (int k = 0; k < 8; ++k) INJc[k] = cbase + (float)k;
    } else {
      float4 ja = *(const float4*)(bndR);
      float4 jb = *(const float4*)(bndR + 4);
      INJc[0] = ja.x; INJc[1] = ja.y; INJc[2] = ja.z; INJc[3] = ja.w;
      INJc[4] = jb.x; INJc[5] = jb.y; INJc[6] = jb.z; INJc[7] = jb.w;
    }
    int W0 = D4, W1 = D5, W2 = D6; dn += 7;

    int s0 = 0;
#define ITER_AB(M) \
    do_iter<M>(s0, lane, wzero, tokd, dn, nlJ, bndR, bndW, a0, W0, W1, W2, \
               XKc0, XKc1, XKn0, XKn1, SBc, INJc, SBn, INJn, ri, cbase, \
               vp0, vp1, vp2, vp3, dgL, m3p, wq0, wq1, wq2, wq3, ans, qh); s0 += 8; \
    do_iter<M>(s0, lane, wzero, tokd, dn, nlJ, bndR, bndW, a0, W0, W1, W2, \
               XKn0, XKn1, XKc0, XKc1, SBn, INJn, SBc, INJc, ri, cbase, \
               vp0, vp1, vp2, vp3, dgL, m3p, wq0, wq1, wq2, wq3, ans, qh); s0 += 8;

    for (int pr = 0; pr < 4; ++pr) { ITER_AB(true) }
    for (int pr = 0; pr < 4; ++pr) { ITER_AB(false) }
    for (int pr = 0; pr < 4; ++pr) { ITER_AB(true) }
#undef ITER_AB
  }

  if (t == 255) partial[b] = ans;
  if (L == 0 && t == 0) partial[b] = P0[NLEN - 1];
}

__global__ void reduce_kernel(const float* __restrict__ partial, float* __restrict__ out) {
  if (threadIdx.x == 0) {
    float s = 0.f;
    for (int b2 = 0; b2 < 32; ++b2) s += partial[b2];
    out[0] = s;
  }
}

extern "C" void kernel_launch(void* const* d_in, const int* in_sizes, int n_in,
                              void* d_out, int out_size, void* d_ws, size_t ws_size,
                              hipStream_t stream) {
  const int*   y_true = (const int*)d_in[0];
  const float* y_pred = (const float*)d_in[1];
  float* out = (float*)d_out;
  float* partial = (float*)d_ws;

  const size_t lds_bytes = (size_t)LDS_FLOATS * sizeof(float);
  hipFuncSetAttribute((const void*)align_loss_kernel,
                      hipFuncAttributeMaxDynamicSharedMemorySize, (int)lds_bytes);

  hipLaunchKernelGGL(align_loss_kernel, dim3(32), dim3(256), lds_bytes, stream,
                     y_true, y_pred, partial);
  hipLaunchKernelGGL(reduce_kernel, dim3(1), dim3(64), 0, stream, partial, out);
}